// Round 6
// baseline (666.272 us; speedup 1.0000x reference)
//
#include <hip/hip_runtime.h>
#include <hip/hip_bf16.h>
#include <math.h>

#define B_ 4
#define L_ 2048
#define D_ 1024
#define E_ 2048
#define N_ 16
#define DD_ 64
#define DCONV_ 4

#define S_SEG 32
#define SEGLEN_ (L_ / S_SEG)   // 64

typedef __attribute__((ext_vector_type(8))) short bf16x8;
typedef __attribute__((ext_vector_type(4))) float f32x4;

typedef __attribute__((address_space(1))) const void gvoid_t;
typedef __attribute__((address_space(3))) void lvoid_t;

static __device__ __forceinline__ float silu_f(float x) {
    return x / (1.f + __expf(-x));
}

static __device__ __forceinline__ ushort f2bf(float f) {
    __hip_bfloat16 h = __float2bfloat16(f);
    return *reinterpret_cast<ushort*>(&h);
}

#define LOG2E_ 1.4426950408889634f

// ---------------- RMSNorm: resid [B*L, D] -> xn (bf16) ----------------
__global__ __launch_bounds__(256) void k_rmsnorm_bf(const float* __restrict__ resid,
                                                    const float* __restrict__ nw,
                                                    ushort* __restrict__ out) {
    int row = blockIdx.x;
    const float* r = resid + (size_t)row * D_;
    int t = threadIdx.x;
    float4 v = *reinterpret_cast<const float4*>(&r[t * 4]);
    float ss = v.x * v.x + v.y * v.y + v.z * v.z + v.w * v.w;
#pragma unroll
    for (int o = 32; o >= 1; o >>= 1) ss += __shfl_xor(ss, o, 64);
    __shared__ float red[4];
    if ((t & 63) == 0) red[t >> 6] = ss;
    __syncthreads();
    float tot = red[0] + red[1] + red[2] + red[3];
    float rs = rsqrtf(tot * (1.f / (float)D_) + 1e-5f);
    float4 w4 = *reinterpret_cast<const float4*>(&nw[t * 4]);
    ushort4 o4;
    o4.x = f2bf(v.x * rs * w4.x);
    o4.y = f2bf(v.y * rs * w4.y);
    o4.z = f2bf(v.z * rs * w4.z);
    o4.w = f2bf(v.w * rs * w4.w);
    *reinterpret_cast<ushort4*>(&out[(size_t)row * D_ + t * 4]) = o4;
}

// ---------------- f32 -> bf16 cast (for weights) ----------------
__global__ __launch_bounds__(256) void k_cast_bf(const float* __restrict__ in,
                                                 ushort* __restrict__ out) {
    int i = blockIdx.x * 256 + threadIdx.x;  // float4 index
    float4 v = *reinterpret_cast<const float4*>(&in[i * 4]);
    ushort4 o;
    o.x = f2bf(v.x); o.y = f2bf(v.y); o.z = f2bf(v.z); o.w = f2bf(v.w);
    *reinterpret_cast<ushort4*>(&out[i * 4]) = o;
}

// ---------------- bf16 MFMA GEMM (global_load_lds staging, m97-style) ----------------
// C[M,N] = A[M,K] @ W[N,K]^T
// EPI: 0 = plain f32 store, 1 = softplus(acc + bias[n]), 2 = += addsrc then store
template <int EPI>
__global__ __launch_bounds__(256) void k_gemm_bf(const ushort* __restrict__ A,
                                                 const ushort* __restrict__ W,
                                                 const float* __restrict__ bias,
                                                 const float* __restrict__ addsrc,
                                                 float* __restrict__ C,
                                                 int M, int N, int K) {
    constexpr int BM = 128, BN = 128, BK = 32;
    __shared__ __align__(16) ushort As[BM * BK];   // linear [128][32]
    __shared__ __align__(16) ushort Ws[BN * BK];
    int t = threadIdx.x;
    int m0 = blockIdx.y * BM, n0 = blockIdx.x * BN;
    int wave = t >> 6, lane = t & 63;
    int wr = wave >> 1, wc = wave & 1;     // wave quadrant (64x64)
    int lr = lane & 15, lg = lane >> 4;    // frag row, k-group
    int srow = lane >> 2;                  // staging: 0..15
    int scol = (lane & 3) * 8;             // staging col (ushort) 0,8,16,24

    f32x4 acc[4][4] = {};

    for (int k0 = 0; k0 < K; k0 += BK) {
#pragma unroll
        for (int p = 0; p < 2; ++p) {
            int seg = wave * 2 + p;        // 0..7, 16 rows each
            int row = seg * 16 + srow;
            __builtin_amdgcn_global_load_lds(
                (gvoid_t*)(A + (size_t)(m0 + row) * K + k0 + scol),
                (lvoid_t*)(As + seg * 512), 16, 0, 0);
            __builtin_amdgcn_global_load_lds(
                (gvoid_t*)(W + (size_t)(n0 + row) * K + k0 + scol),
                (lvoid_t*)(Ws + seg * 512), 16, 0, 0);
        }
        __syncthreads();
        bf16x8 af[4], bfr[4];
#pragma unroll
        for (int i = 0; i < 4; ++i) {
            af[i]  = *reinterpret_cast<const bf16x8*>(&As[(wr * 64 + i * 16 + lr) * BK + lg * 8]);
            bfr[i] = *reinterpret_cast<const bf16x8*>(&Ws[(wc * 64 + i * 16 + lr) * BK + lg * 8]);
        }
#pragma unroll
        for (int i = 0; i < 4; ++i)
#pragma unroll
            for (int j = 0; j < 4; ++j)
                acc[i][j] = __builtin_amdgcn_mfma_f32_16x16x32_bf16(af[i], bfr[j], acc[i][j], 0, 0, 0);
        __syncthreads();
    }

#pragma unroll
    for (int i = 0; i < 4; ++i) {
        int mrow = m0 + wr * 64 + i * 16 + lg * 4;
#pragma unroll
        for (int j = 0; j < 4; ++j) {
            int ncol = n0 + wc * 64 + j * 16 + lr;
#pragma unroll
            for (int q = 0; q < 4; ++q) {
                float v = acc[i][j][q];
                size_t idx = (size_t)(mrow + q) * N + ncol;
                if (EPI == 1) {
                    float z = v + bias[ncol];
                    v = (z > 20.f) ? z : log1pf(expf(z));
                }
                if (EPI == 2) v += addsrc[idx];
                C[idx] = v;
            }
        }
    }
}

// ---------------- fused skinny projections: [Bm|Cm|d1] = xs_bf @ wbc_bf^T ----------------
// wbc rows: 0-15 = WB, 16-31 = WC, 32-95 = Wd1.  M=8192, N=96, K=2048.
__global__ __launch_bounds__(256) void k_proj(const ushort* __restrict__ A,
                                              const ushort* __restrict__ Wc,
                                              float* __restrict__ Bm,
                                              float* __restrict__ Cm,
                                              ushort* __restrict__ d1_bf) {
    constexpr int BK = 32, LDB = 40;
    __shared__ __align__(16) ushort As[32 * LDB];
    __shared__ __align__(16) ushort Ws[96 * LDB];
    int t = threadIdx.x;
    int m0 = blockIdx.x * 32;
    int wave = t >> 6, lane = t & 63;
    int rowbase = (wave >> 1) * 16;
    int colbase = (wave & 1) * 48;
    int lr = lane & 15, lg = lane >> 4;

    f32x4 acc[3] = {};

    for (int k0 = 0; k0 < E_; k0 += BK) {
        if (t < 128) {
            int row = t >> 2;
            int cg = (t & 3) * 8;
            *reinterpret_cast<uint4*>(&As[row * LDB + cg]) =
                *reinterpret_cast<const uint4*>(&A[(size_t)(m0 + row) * E_ + k0 + cg]);
        }
        {
            int f = t;
            int row = f >> 2, cg = (f & 3) * 8;
            *reinterpret_cast<uint4*>(&Ws[row * LDB + cg]) =
                *reinterpret_cast<const uint4*>(&Wc[(size_t)row * E_ + k0 + cg]);
            if (t < 128) {
                int f2 = t + 256;
                int row2 = f2 >> 2, cg2 = (f2 & 3) * 8;
                *reinterpret_cast<uint4*>(&Ws[row2 * LDB + cg2]) =
                    *reinterpret_cast<const uint4*>(&Wc[(size_t)row2 * E_ + k0 + cg2]);
            }
        }
        __syncthreads();
        bf16x8 af = *reinterpret_cast<const bf16x8*>(&As[(rowbase + lr) * LDB + lg * 8]);
#pragma unroll
        for (int j = 0; j < 3; ++j) {
            bf16x8 bf = *reinterpret_cast<const bf16x8*>(&Ws[(colbase + j * 16 + lr) * LDB + lg * 8]);
            acc[j] = __builtin_amdgcn_mfma_f32_16x16x32_bf16(af, bf, acc[j], 0, 0, 0);
        }
        __syncthreads();
    }

#pragma unroll
    for (int j = 0; j < 3; ++j) {
        int ncol = colbase + j * 16 + lr;
#pragma unroll
        for (int q = 0; q < 4; ++q) {
            int m = m0 + rowbase + lg * 4 + q;
            float v = acc[j][q];
            if (ncol < 16)      Bm[(size_t)m * 16 + ncol] = v;
            else if (ncol < 32) Cm[(size_t)m * 16 + (ncol - 16)] = v;
            else                d1_bf[(size_t)m * 64 + (ncol - 32)] = f2bf(v);
        }
    }
}

// ---------------- depthwise causal conv1d + bias + silu (f32 + bf16 out) ----------------
__global__ __launch_bounds__(256) void k_conv_silu(const float* __restrict__ x,
                                                   const float* __restrict__ w,
                                                   const float* __restrict__ bias,
                                                   float* __restrict__ out,
                                                   ushort* __restrict__ out_bf) {
    int idx = blockIdx.x * 256 + threadIdx.x;
    int e = idx & (E_ - 1);
    int l = (idx / E_) & (L_ - 1);
    float4 wv = *reinterpret_cast<const float4*>(&w[e * 4]);
    float acc = bias[e];
    acc = fmaf(wv.w, x[idx], acc);
    if (l >= 1) acc = fmaf(wv.z, x[idx - E_], acc);
    if (l >= 2) acc = fmaf(wv.y, x[idx - 2 * E_], acc);
    if (l >= 3) acc = fmaf(wv.x, x[idx - 3 * E_], acc);
    float s = silu_f(acc);
    out[idx] = s;
    out_bf[idx] = f2bf(s);
}

// ================= segmented selective scan: 1 lane = 1 channel =================
// h after segment s = h_loc[s] + exp(A*sum(delta_seg)) * h_in[s].
// p1: local scans -> hbuf(=h_loc), sdsum.  p2: in-place chain (hbuf -> h_in).
// p3: full scan per segment from h_in, fused W_D add + silu(skip) gate -> bf16.
// d/x/skip loads are lane-coalesced (e fastest); B/C loads wave-uniform.

__global__ __launch_bounds__(256) void k_scan_p1(const float* __restrict__ xs,
                                                 const float* __restrict__ delta,
                                                 const float* __restrict__ Bm,
                                                 const float* __restrict__ A_log,
                                                 float* __restrict__ hbuf,
                                                 float* __restrict__ sdsum) {
    int t = threadIdx.x;
    int bid = blockIdx.x;
    int s = bid & (S_SEG - 1);
    int eblk = (bid >> 5) & 7;
    int b = bid >> 8;
    int e = eblk * 256 + t;

    float A2[16];
#pragma unroll
    for (int i = 0; i < 16; i += 4) {
        f32x4 al = *reinterpret_cast<const f32x4*>(&A_log[(size_t)e * 16 + i]);
#pragma unroll
        for (int j = 0; j < 4; ++j) A2[i + j] = -__expf(al[j]) * LOG2E_;
    }
    f32x4 h4[4] = {};
    float sdl = 0.f;

    const float* dp = delta + ((size_t)b * L_ + s * SEGLEN_) * E_ + e;
    const float* xp = xs    + ((size_t)b * L_ + s * SEGLEN_) * E_ + e;
    const float* Bp = Bm + ((size_t)b * L_ + s * SEGLEN_) * 16;

#pragma unroll 2
    for (int l = 0; l < SEGLEN_; ++l) {
        float d  = dp[(size_t)l * E_];
        float xv = xp[(size_t)l * E_];
        f32x4 B4[4];
#pragma unroll
        for (int g = 0; g < 4; ++g)
            B4[g] = *reinterpret_cast<const f32x4*>(&Bp[l * 16 + g * 4]);
        float dx = d * xv;
        sdl += d;
#pragma unroll
        for (int g = 0; g < 4; ++g) {
            f32x4 e4;
#pragma unroll
            for (int j = 0; j < 4; ++j) e4[j] = exp2f(d * A2[g * 4 + j]);
            h4[g] = e4 * h4[g] + dx * B4[g];
        }
    }
    size_t cidx = ((size_t)(b * S_SEG + s) * E_ + e) * 16;
#pragma unroll
    for (int g = 0; g < 4; ++g)
        *reinterpret_cast<f32x4*>(&hbuf[cidx + g * 4]) = h4[g];
    sdsum[(size_t)(b * S_SEG + s) * E_ + e] = sdl;
}

__global__ __launch_bounds__(256) void k_scan_p2(float* __restrict__ hbuf,
                                                 const float* __restrict__ sdsum,
                                                 const float* __restrict__ A_log) {
    int t = blockIdx.x * 256 + threadIdx.x;   // B*E*4 threads
    int q = t & 3;
    int e = (t >> 2) & (E_ - 1);
    int b = t >> 13;
    f32x4 A2;
    {
        f32x4 al = *reinterpret_cast<const f32x4*>(&A_log[(size_t)e * 16 + q * 4]);
#pragma unroll
        for (int i = 0; i < 4; ++i) A2[i] = -__expf(al[i]) * LOG2E_;
    }
    f32x4 acc = {0.f, 0.f, 0.f, 0.f};
    for (int s = 0; s < S_SEG; ++s) {
        size_t idx = ((size_t)(b * S_SEG + s) * E_ + e) * 16 + q * 4;
        f32x4 hl = *reinterpret_cast<const f32x4*>(&hbuf[idx]);
        float sd = sdsum[(size_t)(b * S_SEG + s) * E_ + e];
        *reinterpret_cast<f32x4*>(&hbuf[idx]) = acc;   // hbuf becomes h_in
        f32x4 p;
#pragma unroll
        for (int i = 0; i < 4; ++i) p[i] = exp2f(A2[i] * sd);
        acc = hl + p * acc;
    }
}

__global__ __launch_bounds__(256) void k_scan_p3(const float* __restrict__ xs,
                                                 const float* __restrict__ delta,
                                                 const float* __restrict__ Bm,
                                                 const float* __restrict__ Cm,
                                                 const float* __restrict__ A_log,
                                                 const float* __restrict__ W_D,
                                                 const float* __restrict__ skip,
                                                 const float* __restrict__ hbuf,
                                                 ushort* __restrict__ yg) {
    int t = threadIdx.x;
    int bid = blockIdx.x;
    int s = bid & (S_SEG - 1);
    int eblk = (bid >> 5) & 7;
    int b = bid >> 8;
    int e = eblk * 256 + t;

    float A2[16];
#pragma unroll
    for (int i = 0; i < 16; i += 4) {
        f32x4 al = *reinterpret_cast<const f32x4*>(&A_log[(size_t)e * 16 + i]);
#pragma unroll
        for (int j = 0; j < 4; ++j) A2[i + j] = -__expf(al[j]) * LOG2E_;
    }
    size_t cidx = ((size_t)(b * S_SEG + s) * E_ + e) * 16;
    f32x4 h4[4];
#pragma unroll
    for (int g = 0; g < 4; ++g)
        h4[g] = *reinterpret_cast<const f32x4*>(&hbuf[cidx + g * 4]);
    float wd = W_D[e];

    const float* dp = delta + ((size_t)b * L_ + s * SEGLEN_) * E_ + e;
    const float* xp = xs    + ((size_t)b * L_ + s * SEGLEN_) * E_ + e;
    const float* sp = skip  + ((size_t)b * L_ + s * SEGLEN_) * E_ + e;
    const float* Bp = Bm + ((size_t)b * L_ + s * SEGLEN_) * 16;
    const float* Cp = Cm + ((size_t)b * L_ + s * SEGLEN_) * 16;
    ushort* yp = yg + ((size_t)b * L_ + s * SEGLEN_) * E_ + e;

#pragma unroll 2
    for (int l = 0; l < SEGLEN_; ++l) {
        float d  = dp[(size_t)l * E_];
        float xv = xp[(size_t)l * E_];
        float sk = sp[(size_t)l * E_];
        f32x4 B4[4], C4[4];
#pragma unroll
        for (int g = 0; g < 4; ++g) {
            B4[g] = *reinterpret_cast<const f32x4*>(&Bp[l * 16 + g * 4]);
            C4[g] = *reinterpret_cast<const f32x4*>(&Cp[l * 16 + g * 4]);
        }
        float dx = d * xv;
        f32x4 yv = {0.f, 0.f, 0.f, 0.f};
#pragma unroll
        for (int g = 0; g < 4; ++g) {
            f32x4 e4;
#pragma unroll
            for (int j = 0; j < 4; ++j) e4[j] = exp2f(d * A2[g * 4 + j]);
            h4[g] = e4 * h4[g] + dx * B4[g];
            yv = h4[g] * C4[g] + yv;
        }
        float y = (yv[0] + yv[1]) + (yv[2] + yv[3]);
        float gsk = silu_f(sk);
        yp[(size_t)l * E_] = f2bf((y + xv * wd) * gsk);
    }
}

extern "C" void kernel_launch(void* const* d_in, const int* in_sizes, int n_in,
                              void* d_out, int out_size, void* d_ws, size_t ws_size,
                              hipStream_t stream) {
    const float* resid  = (const float*)d_in[0];
    const float* norm_w = (const float*)d_in[1];
    const float* skip_w = (const float*)d_in[2];
    const float* in_w   = (const float*)d_in[3];
    const float* conv_w = (const float*)d_in[4];
    const float* conv_b = (const float*)d_in[5];
    const float* Wd1    = (const float*)d_in[6];
    const float* Wd2_w  = (const float*)d_in[7];
    const float* Wd2_b  = (const float*)d_in[8];
    const float* WB     = (const float*)d_in[9];
    const float* WC     = (const float*)d_in[10];
    const float* A_log  = (const float*)d_in[11];
    const float* W_D    = (const float*)d_in[12];
    const float* out_w  = (const float*)d_in[13];
    float* out = (float*)d_out;

    const int M = B_ * L_;                 // 8192
    char* p = (char*)d_ws;
    ushort* xn_bf   = (ushort*)p;  p += (size_t)M * D_ * 2;   // 16.8 MB
    ushort* skw_bf  = (ushort*)p;  p += (size_t)E_ * D_ * 2;  // 4.2 MB
    ushort* inw_bf  = (ushort*)p;  p += (size_t)E_ * D_ * 2;
    ushort* outw_bf = (ushort*)p;  p += (size_t)D_ * E_ * 2;
    ushort* yg_bf   = (ushort*)p;  p += (size_t)M * E_ * 2;   // also xs_bf (alias)
    float*  skipb   = (float*)p;   p += (size_t)M * E_ * 4;
    float*  xin     = (float*)p;   p += (size_t)M * E_ * 4;   // also delta (alias)
    float*  xs      = (float*)p;   p += (size_t)M * E_ * 4;
    ushort* d1_bf   = (ushort*)p;  p += (size_t)M * DD_ * 2;
    float*  Bm      = (float*)p;   p += (size_t)M * 16 * 4;
    float*  Cm      = (float*)p;   p += (size_t)M * 16 * 4;
    ushort* wbc_bf  = (ushort*)p;  p += (size_t)96 * E_ * 2;  // [WB;WC;Wd1] bf16
    ushort* wd2_bf  = (ushort*)p;  p += (size_t)E_ * DD_ * 2;
    float*  delta   = xin;
    ushort* xs_bf   = yg_bf;       // alias: xs_bf dead before p3 writes yg
    // scan scratch aliases xn_bf (+skw_bf tail), both dead after GEMMs 2/3:
    // hbuf = B*32 segs * E * 16 * 4B = 16.8 MB (exactly xn_bf); sdsum 1 MB in skw_bf.
    float*  hbuf    = (float*)xn_bf;
    float*  sdsum   = hbuf + (size_t)B_ * S_SEG * E_ * 16;

    dim3 blk(256);

    // weight casts
    k_cast_bf<<<dim3((E_ * D_) / 1024), blk, 0, stream>>>(skip_w, skw_bf);
    k_cast_bf<<<dim3((E_ * D_) / 1024), blk, 0, stream>>>(in_w, inw_bf);
    k_cast_bf<<<dim3((D_ * E_) / 1024), blk, 0, stream>>>(out_w, outw_bf);
    k_cast_bf<<<dim3((N_ * E_) / 1024), blk, 0, stream>>>(WB, wbc_bf);
    k_cast_bf<<<dim3((N_ * E_) / 1024), blk, 0, stream>>>(WC, wbc_bf + (size_t)16 * E_);
    k_cast_bf<<<dim3((DD_ * E_) / 1024), blk, 0, stream>>>(Wd1, wbc_bf + (size_t)32 * E_);
    k_cast_bf<<<dim3((E_ * DD_) / 1024), blk, 0, stream>>>(Wd2_w, wd2_bf);
    // 1. RMSNorm -> bf16
    k_rmsnorm_bf<<<dim3(M), blk, 0, stream>>>(resid, norm_w, xn_bf);
    // 2. skip = xn @ skip_w^T   [M,E]
    k_gemm_bf<0><<<dim3(E_ / 128, M / 128), blk, 0, stream>>>(xn_bf, skw_bf, nullptr, nullptr, skipb, M, E_, D_);
    // 3. xin = xn @ in_w^T      [M,E]
    k_gemm_bf<0><<<dim3(E_ / 128, M / 128), blk, 0, stream>>>(xn_bf, inw_bf, nullptr, nullptr, xin, M, E_, D_);
    // 4. xs = silu(conv(xin)+b), also bf16 copy
    k_conv_silu<<<dim3((M * E_) / 256), blk, 0, stream>>>(xin, conv_w, conv_b, xs, xs_bf);
    // 5+7. fused skinny projections: Bm, Cm, d1_bf = xs_bf @ [WB;WC;Wd1]^T
    k_proj<<<dim3(M / 32), blk, 0, stream>>>(xs_bf, wbc_bf, Bm, Cm, d1_bf);
    // 6. delta = softplus(d1 @ Wd2^T + b) [M,E]  (bf16 MFMA, K=64)
    k_gemm_bf<1><<<dim3(E_ / 128, M / 128), blk, 0, stream>>>(d1_bf, wd2_bf, Wd2_b, nullptr, delta, M, E_, DD_);
    // 8. segmented scan: p1 local scans -> hbuf, p2 in-place chain, p3 gated output
    k_scan_p1<<<dim3(B_ * S_SEG * (E_ / 256)), blk, 0, stream>>>(xs, delta, Bm, A_log, hbuf, sdsum);
    k_scan_p2<<<dim3((B_ * E_ * 4) / 256), blk, 0, stream>>>(hbuf, sdsum, A_log);
    k_scan_p3<<<dim3(B_ * S_SEG * (E_ / 256)), blk, 0, stream>>>(xs, delta, Bm, Cm, A_log, W_D,
                                                                  skipb, hbuf, yg_bf);
    // 9. out = resid + yg @ out_w^T
    k_gemm_bf<2><<<dim3(D_ / 128, M / 128), blk, 0, stream>>>(yg_bf, outw_bf, nullptr, resid, out, M, D_, E_);
}